// Round 5
// baseline (1847.269 us; speedup 1.0000x reference)
//
#include <hip/hip_runtime.h>
#include <math.h>

#define NCLS 9

typedef __attribute__((ext_vector_type(8))) short short8;
typedef __attribute__((ext_vector_type(4))) float f32x4;

__device__ __forceinline__ unsigned short f2bf(float f) {
    unsigned int u = __float_as_uint(f);
    return (unsigned short)((u + 0x7fffu + ((u >> 16) & 1u)) >> 16);  // RNE
}

__device__ __forceinline__ short8 as_s8(uint4 v) {
    union { uint4 u; short8 s; } x; x.u = v; return x.s;
}

__device__ __forceinline__ float fast_tanh(float x) {
    // tanh(x) = 1 - 2/(2^(x*2*log2e) + 1); saturates correctly at +/-1
    float s = x * 2.885390081777927f;
    float e, r;
    asm("v_exp_f32 %0, %1" : "=v"(e) : "v"(s));
    asm("v_rcp_f32 %0, %1" : "=v"(r) : "v"(e + 1.0f));
    return fmaf(-2.0f, r, 1.0f);
}

// Fused 2-layer persistent MFMA RNN with TWO independent batch groups per
// block (32 rows). 16 blocks x 256 threads (4 waves). Wave w owns 64 output
// cols as 4 B-tiles in registers -- SHARED between both groups (U identical),
// so the second group costs only A-frags + accumulators (~290 VGPR total).
// The two groups' per-step chains are register-independent -> group Y's
// reads/MFMA issue under group X's trans-heavy epilogue (latency hiding that
// the workgroup barrier otherwise destroys).
__global__ __launch_bounds__(256, 1) void rnn_fused_kernel(
    const float* __restrict__ x,     // [B, 1024]
    const float* __restrict__ W1, const float* __restrict__ U1, const float* __restrict__ b1,
    const float* __restrict__ W2, const float* __restrict__ U2, const float* __restrict__ b2,
    float* __restrict__ h2out)       // [B, 256]
{
    const int tid  = threadIdx.x;
    const int w    = tid >> 6;
    const int lane = tid & 63;
    const int g    = lane >> 4;
    const int l16  = lane & 15;
    const int b0   = blockIdx.x << 5;   // 32 rows per block

    __shared__ unsigned char h_lds[2][2][8192];  // [group][buf] 512 cells x 16B
    __shared__ float xchunk[2][128][16];         // [group][t][row]
    __shared__ float seq2[2][256][16];           // [group][col][row] = h1

    // h-write addressing (within a group's 8KB buffer): cols c = w*64+l16*4+t4
    const int cidx  = w * 8 + ((l16 >> 3) << 2) + ((l16 >> 1) & 3);
    const int phi   = cidx & 7;
    const int wbase = cidx * 256 + ((l16 & 1) << 3);
    const int crow  = g * 4;

#pragma unroll 1
    for (int p = 0; p < 2; ++p) {
        const float* W    = p ? W2 : W1;
        const float* U    = p ? U2 : U1;
        const float* bias = p ? b2 : b1;
        const int    T    = p ? 256 : 1024;

        // ---- B-fragments for this layer's U (bf16, registers, shared) ----
        uint4 bfrag[4][8];
        {
            const int colbase = w * 64 + l16 * 4;
            #pragma unroll
            for (int t4 = 0; t4 < 4; ++t4) {
                #pragma unroll
                for (int kk = 0; kk < 8; ++kk) {
                    unsigned int d[4];
                    #pragma unroll
                    for (int pr = 0; pr < 4; ++pr) {
                        const int k0 = kk * 32 + g * 8 + 2 * pr;
                        d[pr] = (unsigned)f2bf(U[k0 * 256 + colbase + t4])
                              | ((unsigned)f2bf(U[(k0 + 1) * 256 + colbase + t4]) << 16);
                    }
                    bfrag[t4][kk] = make_uint4(d[0], d[1], d[2], d[3]);
                }
            }
        }
        #pragma unroll
        for (int t4 = 0; t4 < 4; ++t4)
            #pragma unroll
            for (int kk = 0; kk < 8; ++kk)
                asm volatile("" : "+v"(bfrag[t4][kk].x), "+v"(bfrag[t4][kk].y),
                                  "+v"(bfrag[t4][kk].z), "+v"(bfrag[t4][kk].w));

        const float4 wv = *(const float4*)&W[w * 64 + l16 * 4];
        const float4 bv = *(const float4*)&bias[w * 64 + l16 * 4];
        const float wvr[4] = {wv.x, wv.y, wv.z, wv.w};
        const float bvr[4] = {bv.x, bv.y, bv.z, bv.w};

        // zero buf 0 of both groups
        for (int idx = tid; idx < 4096; idx += 256)
            ((unsigned int*)h_lds[idx >> 11][0])[idx & 2047] = 0u;
        __syncthreads();

        for (int t = 0; t < T; ++t) {
            if (p == 0 && (t & 127) == 0) {
                // prefetch 128 steps x 32 rows, coalesced
                for (int idx = tid; idx < 4096; idx += 256) {
                    const int gi = idx >> 11, rem = idx & 2047;
                    const int row = rem >> 7, dt = rem & 127;
                    xchunk[gi][dt][row] = x[(b0 + gi * 16 + row) * 1024 + t + dt];
                }
                __syncthreads();
            }
            const int cur = t & 1;
            const int nxt = cur ^ 1;

            // ---- issue both groups' A-reads up front ----
            uint4 aX[8], aY[8];
            #pragma unroll
            for (int kk = 0; kk < 8; ++kk) {
                const int cell = ((kk * 64 + g * 16 + l16) ^ ((kk * 4 + g) & 7)) << 4;
                aX[kk] = *(const uint4*)&h_lds[0][cur][cell];
                aY[kk] = *(const uint4*)&h_lds[1][cur][cell];
            }
            const float4 svX = p ? *(const float4*)&seq2[0][t][crow]
                                 : *(const float4*)&xchunk[0][t & 127][crow];
            const float4 svY = p ? *(const float4*)&seq2[1][t][crow]
                                 : *(const float4*)&xchunk[1][t & 127][crow];

            // ---- MFMA group X then group Y (independent chains) ----
            f32x4 accAX[4], accBX[4], accAY[4], accBY[4];
            #pragma unroll
            for (int t4 = 0; t4 < 4; ++t4) {
                accAX[t4] = (f32x4){0.f, 0.f, 0.f, 0.f};
                accBX[t4] = (f32x4){0.f, 0.f, 0.f, 0.f};
                accAY[t4] = (f32x4){0.f, 0.f, 0.f, 0.f};
                accBY[t4] = (f32x4){0.f, 0.f, 0.f, 0.f};
            }
            #pragma unroll
            for (int kp = 0; kp < 4; ++kp) {
                #pragma unroll
                for (int t4 = 0; t4 < 4; ++t4) {
                    accAX[t4] = __builtin_amdgcn_mfma_f32_16x16x32_bf16(
                        as_s8(aX[2 * kp]), as_s8(bfrag[t4][2 * kp]), accAX[t4], 0, 0, 0);
                    accBX[t4] = __builtin_amdgcn_mfma_f32_16x16x32_bf16(
                        as_s8(aX[2 * kp + 1]), as_s8(bfrag[t4][2 * kp + 1]), accBX[t4], 0, 0, 0);
                }
            }
            #pragma unroll
            for (int kp = 0; kp < 4; ++kp) {
                #pragma unroll
                for (int t4 = 0; t4 < 4; ++t4) {
                    accAY[t4] = __builtin_amdgcn_mfma_f32_16x16x32_bf16(
                        as_s8(aY[2 * kp]), as_s8(bfrag[t4][2 * kp]), accAY[t4], 0, 0, 0);
                    accBY[t4] = __builtin_amdgcn_mfma_f32_16x16x32_bf16(
                        as_s8(aY[2 * kp + 1]), as_s8(bfrag[t4][2 * kp + 1]), accBY[t4], 0, 0, 0);
                }
            }

            // ---- epilogue group X ----
            {
                const float svr[4] = {svX.x, svX.y, svX.z, svX.w};
                #pragma unroll
                for (int r = 0; r < 4; ++r) {
                    float hf[4];
                    #pragma unroll
                    for (int t4 = 0; t4 < 4; ++t4) {
                        const float v = (accAX[t4][r] + accBX[t4][r])
                                      + fmaf(svr[r], wvr[t4], bvr[t4]);
                        hf[t4] = fast_tanh(v);
                    }
                    unsigned lo, hi;
                    asm("v_cvt_pk_bf16_f32 %0, %1, %2" : "=v"(lo) : "v"(hf[0]), "v"(hf[1]));
                    asm("v_cvt_pk_bf16_f32 %0, %1, %2" : "=v"(hi) : "v"(hf[2]), "v"(hf[3]));
                    const int rowx = (crow + r) ^ phi;
                    *(uint2*)&h_lds[0][nxt][wbase + (rowx << 4)] = make_uint2(lo, hi);
                    if (t == T - 1) {
                        const int colb = w * 64 + l16 * 4;
                        if (p == 0) {
                            #pragma unroll
                            for (int t4 = 0; t4 < 4; ++t4)
                                seq2[0][colb + t4][crow + r] = hf[t4];
                        } else {
                            *(float4*)&h2out[(b0 + crow + r) * 256 + colb] =
                                make_float4(hf[0], hf[1], hf[2], hf[3]);
                        }
                    }
                }
            }
            // ---- epilogue group Y ----
            {
                const float svr[4] = {svY.x, svY.y, svY.z, svY.w};
                #pragma unroll
                for (int r = 0; r < 4; ++r) {
                    float hf[4];
                    #pragma unroll
                    for (int t4 = 0; t4 < 4; ++t4) {
                        const float v = (accAY[t4][r] + accBY[t4][r])
                                      + fmaf(svr[r], wvr[t4], bvr[t4]);
                        hf[t4] = fast_tanh(v);
                    }
                    unsigned lo, hi;
                    asm("v_cvt_pk_bf16_f32 %0, %1, %2" : "=v"(lo) : "v"(hf[0]), "v"(hf[1]));
                    asm("v_cvt_pk_bf16_f32 %0, %1, %2" : "=v"(hi) : "v"(hf[2]), "v"(hf[3]));
                    const int rowx = (crow + r) ^ phi;
                    *(uint2*)&h_lds[1][nxt][wbase + (rowx << 4)] = make_uint2(lo, hi);
                    if (t == T - 1) {
                        const int colb = w * 64 + l16 * 4;
                        if (p == 0) {
                            #pragma unroll
                            for (int t4 = 0; t4 < 4; ++t4)
                                seq2[1][colb + t4][crow + r] = hf[t4];
                        } else {
                            *(float4*)&h2out[(b0 + 16 + crow + r) * 256 + colb] =
                                make_float4(hf[0], hf[1], hf[2], hf[3]);
                        }
                    }
                }
            }
            __syncthreads();
        }
    }
}

// Tiny MLP head: one block per batch row, 128 threads.
__global__ __launch_bounds__(128) void mlp_kernel(
    const float* __restrict__ h2,
    const float* __restrict__ Wd1, const float* __restrict__ bd1,
    const float* __restrict__ Wd2, const float* __restrict__ bd2,
    const float* __restrict__ Wd3, const float* __restrict__ bd3,
    const float* __restrict__ Wd4, const float* __restrict__ bd4,
    float* __restrict__ out)
{
    const int b   = blockIdx.x;
    const int tid = threadIdx.x;

    __shared__ float hin[256];
    __shared__ float z1[128];
    __shared__ float z2[64];
    __shared__ float z3[32];

    hin[tid]       = h2[b * 256 + tid];
    hin[tid + 128] = h2[b * 256 + tid + 128];
    __syncthreads();

    {
        float a = bd1[tid];
#pragma unroll 8
        for (int i = 0; i < 256; ++i) a += hin[i] * Wd1[i * 128 + tid];
        z1[tid] = fmaxf(a, 0.0f);
    }
    __syncthreads();
    if (tid < 64) {
        float a = bd2[tid];
#pragma unroll 8
        for (int i = 0; i < 128; ++i) a += z1[i] * Wd2[i * 64 + tid];
        z2[tid] = fmaxf(a, 0.0f);
    }
    __syncthreads();
    if (tid < 32) {
        float a = bd3[tid];
#pragma unroll 8
        for (int i = 0; i < 64; ++i) a += z2[i] * Wd3[i * 32 + tid];
        z3[tid] = fmaxf(a, 0.0f);
    }
    __syncthreads();
    if (tid < NCLS) {
        float a = bd4[tid];
#pragma unroll
        for (int i = 0; i < 32; ++i) a += z3[i] * Wd4[i * NCLS + tid];
        out[b * NCLS + tid] = a;
    }
}

extern "C" void kernel_launch(void* const* d_in, const int* in_sizes, int n_in,
                              void* d_out, int out_size, void* d_ws, size_t ws_size,
                              hipStream_t stream) {
    const float* x   = (const float*)d_in[0];
    const float* W1  = (const float*)d_in[1];
    const float* U1  = (const float*)d_in[2];
    const float* b1  = (const float*)d_in[3];
    const float* W2  = (const float*)d_in[4];
    const float* U2  = (const float*)d_in[5];
    const float* b2  = (const float*)d_in[6];
    const float* Wd1 = (const float*)d_in[7];
    const float* bd1 = (const float*)d_in[8];
    const float* Wd2 = (const float*)d_in[9];
    const float* bd2 = (const float*)d_in[10];
    const float* Wd3 = (const float*)d_in[11];
    const float* bd3 = (const float*)d_in[12];
    const float* Wd4 = (const float*)d_in[13];
    const float* bd4 = (const float*)d_in[14];

    float* out = (float*)d_out;
    float* h2  = (float*)d_ws;        // 512*256 fp32

    rnn_fused_kernel<<<16, 256, 0, stream>>>(x, W1, U1, b1, W2, U2, b2, h2);
    mlp_kernel<<<512, 128, 0, stream>>>(h2, Wd1, bd1, Wd2, bd2, Wd3, bd3, Wd4, bd4, out);
}

// Round 6
// 790.064 us; speedup vs baseline: 2.3381x; 2.3381x over previous
//
#include <hip/hip_runtime.h>
#include <math.h>

#define NCLS 9

typedef __attribute__((ext_vector_type(8))) short short8;
typedef __attribute__((ext_vector_type(4))) float f32x4;

__device__ __forceinline__ unsigned short f2bf(float f) {
    unsigned int u = __float_as_uint(f);
    return (unsigned short)((u + 0x7fffu + ((u >> 16) & 1u)) >> 16);  // RNE
}

__device__ __forceinline__ short8 as_s8(uint4 v) {
    union { uint4 u; short8 s; } x; x.u = v; return x.s;
}

__device__ __forceinline__ float fast_tanh(float x) {
    // tanh(x) = 1 - 2/(2^(x*2*log2e) + 1); saturates correctly at +/-1
    float s = x * 2.885390081777927f;
    float e, r;
    asm("v_exp_f32 %0, %1" : "=v"(e) : "v"(s));
    asm("v_rcp_f32 %0, %1" : "=v"(r) : "v"(e + 1.0f));
    return fmaf(-2.0f, r, 1.0f);
}

// Fused 2-layer persistent MFMA RNN. 32 blocks x 16 batch rows, 512 threads
// (8 waves). Wave w owns 32 output cols (2 B-tiles, 64 pinned VGPR) with the
// paired-column map col = w*32 + 2c + t2 (c = lane&15) so each row's 2 outputs
// pack to one b32 LDS write via v_cvt_pk_bf16_f32.
//
// h LDS layout: 512 cells x 16B; logical cell (kk,g2,m) holds k = kk*32+g2*8+e
// (e=0..7, bf16) of row m, stored at index kk*64+g2*16+(m ^ ((4*kk+g2)&15)).
//  - A-read (per kk, lanes (g,l16)): 64 distinct cells = contiguous 1KB region
//    permuted -> conflict-free ds_read_b128.
//  - h-write: b32 at cell(w, l16>>2, 4g+r) + 4*(l16&3): banks
//    16*((g^w)&1) + 4*(r^(l16>>2)) + (l16&3) -> exactly 2-way (free).
// All of x staged in LDS once (64KB) -> no global traffic in the step loop.
__global__ __launch_bounds__(512, 2) void rnn_fused_kernel(
    const float* __restrict__ x,     // [B, 1024]
    const float* __restrict__ W1, const float* __restrict__ U1, const float* __restrict__ b1,
    const float* __restrict__ W2, const float* __restrict__ U2, const float* __restrict__ b2,
    float* __restrict__ h2out)       // [B, 256]
{
    const int tid  = threadIdx.x;
    const int w    = tid >> 6;
    const int lane = tid & 63;
    const int g    = lane >> 4;
    const int l16  = lane & 15;
    const int b0   = blockIdx.x << 4;

    __shared__ uint4 hbuf[2][512];       // 2 x 8KB, cell layout above
    __shared__ float xall[1024][16];     // 64KB: x staged [t][row]
    __shared__ float seq2[256][16];      // 16KB: layer-2 input [col][row]

    // ---- stage all of x (once) + zero h buffer 0 ----
    {
        const float4* x4 = (const float4*)x;
        #pragma unroll
        for (int i = 0; i < 8; ++i) {
            const int idx = tid + i * 512;
            const int row = idx >> 8, tq = idx & 255;
            const float4 v = x4[(b0 + row) * 256 + tq];
            xall[tq * 4 + 0][row] = v.x;
            xall[tq * 4 + 1][row] = v.y;
            xall[tq * 4 + 2][row] = v.z;
            xall[tq * 4 + 3][row] = v.w;
        }
        for (int idx = tid; idx < 2048; idx += 512)
            ((unsigned int*)hbuf[0])[idx] = 0u;
    }

    // ---- hoisted LDS byte offsets ----
    int rd_off[8];
    #pragma unroll
    for (int kk = 0; kk < 8; ++kk)
        rd_off[kk] = ((kk * 64 + g * 16) + (l16 ^ ((kk * 4 + g) & 15))) << 4;
    const int q = l16 >> 2, s4 = l16 & 3;
    int wr_off[4];
    #pragma unroll
    for (int r = 0; r < 4; ++r) {
        const int m = 4 * g + r;
        wr_off[r] = (((w * 64 + q * 16) + (m ^ ((4 * w + q) & 15))) << 4) + 4 * s4;
    }
    const int col0 = w * 32 + 2 * l16;
    char* const hbase = (char*)hbuf;

#pragma unroll 1
    for (int p = 0; p < 2; ++p) {
        const float* W    = p ? W2 : W1;
        const float* U    = p ? U2 : U1;
        const float* bias = p ? b2 : b1;
        const int    T    = p ? 256 : 1024;

        // ---- B-fragments (bf16, pinned registers); col = w*32 + 2c + t2 ----
        uint4 bfrag[2][8];
        #pragma unroll
        for (int t2 = 0; t2 < 2; ++t2) {
            #pragma unroll
            for (int kk = 0; kk < 8; ++kk) {
                unsigned int d[4];
                #pragma unroll
                for (int pr = 0; pr < 4; ++pr) {
                    const int k0 = kk * 32 + g * 8 + 2 * pr;
                    d[pr] = (unsigned)f2bf(U[k0 * 256 + col0 + t2])
                          | ((unsigned)f2bf(U[(k0 + 1) * 256 + col0 + t2]) << 16);
                }
                bfrag[t2][kk] = make_uint4(d[0], d[1], d[2], d[3]);
            }
        }
        #pragma unroll
        for (int t2 = 0; t2 < 2; ++t2)
            #pragma unroll
            for (int kk = 0; kk < 8; ++kk)
                asm volatile("" : "+v"(bfrag[t2][kk].x), "+v"(bfrag[t2][kk].y),
                                  "+v"(bfrag[t2][kk].z), "+v"(bfrag[t2][kk].w));

        const float2 wv2 = *(const float2*)&W[col0];
        const float2 bv2 = *(const float2*)&bias[col0];

        if (p == 1) {
            // re-zero h buffer 0 for layer 2
            for (int idx = tid; idx < 2048; idx += 512)
                ((unsigned int*)hbuf[0])[idx] = 0u;
        }
        __syncthreads();

        for (int t = 0; t < T; ++t) {
            char* const hcur = hbase + ((t & 1) << 13);
            char* const hnxt = hbase + (((t & 1) ^ 1) << 13);

            // A-fragments: 8 x ds_read_b128, conflict-free
            uint4 a[8];
            #pragma unroll
            for (int kk = 0; kk < 8; ++kk)
                a[kk] = *(const uint4*)(hcur + rd_off[kk]);

            const float4 sv = p ? *(const float4*)&seq2[t][4 * g]
                                : *(const float4*)&xall[t][4 * g];

            // 4 independent 4-deep MFMA chains (2 tiles x even/odd kk)
            f32x4 aA0 = {0.f,0.f,0.f,0.f}, aB0 = {0.f,0.f,0.f,0.f};
            f32x4 aA1 = {0.f,0.f,0.f,0.f}, aB1 = {0.f,0.f,0.f,0.f};
            #pragma unroll
            for (int kp = 0; kp < 4; ++kp) {
                aA0 = __builtin_amdgcn_mfma_f32_16x16x32_bf16(
                    as_s8(a[2 * kp]), as_s8(bfrag[0][2 * kp]), aA0, 0, 0, 0);
                aA1 = __builtin_amdgcn_mfma_f32_16x16x32_bf16(
                    as_s8(a[2 * kp]), as_s8(bfrag[1][2 * kp]), aA1, 0, 0, 0);
                aB0 = __builtin_amdgcn_mfma_f32_16x16x32_bf16(
                    as_s8(a[2 * kp + 1]), as_s8(bfrag[0][2 * kp + 1]), aB0, 0, 0, 0);
                aB1 = __builtin_amdgcn_mfma_f32_16x16x32_bf16(
                    as_s8(a[2 * kp + 1]), as_s8(bfrag[1][2 * kp + 1]), aB1, 0, 0, 0);
            }

            const float svr[4] = {sv.x, sv.y, sv.z, sv.w};
            #pragma unroll
            for (int r = 0; r < 4; ++r) {
                const float v0 = (aA0[r] + aB0[r]) + fmaf(svr[r], wv2.x, bv2.x);
                const float v1 = (aA1[r] + aB1[r]) + fmaf(svr[r], wv2.y, bv2.y);
                const float h0 = fast_tanh(v0);
                const float h1 = fast_tanh(v1);
                unsigned pk;
                asm("v_cvt_pk_bf16_f32 %0, %1, %2" : "=v"(pk) : "v"(h0), "v"(h1));
                *(unsigned int*)(hnxt + wr_off[r]) = pk;

                if (t == T - 1) {
                    const int m = 4 * g + r;
                    if (p == 0) {
                        seq2[col0][m]     = h0;
                        seq2[col0 + 1][m] = h1;
                    } else {
                        *(float2*)&h2out[(b0 + m) * 256 + col0] = make_float2(h0, h1);
                    }
                }
            }
            __syncthreads();
        }
    }
}

// Tiny MLP head: one block per batch row, 128 threads.
__global__ __launch_bounds__(128) void mlp_kernel(
    const float* __restrict__ h2,
    const float* __restrict__ Wd1, const float* __restrict__ bd1,
    const float* __restrict__ Wd2, const float* __restrict__ bd2,
    const float* __restrict__ Wd3, const float* __restrict__ bd3,
    const float* __restrict__ Wd4, const float* __restrict__ bd4,
    float* __restrict__ out)
{
    const int b   = blockIdx.x;
    const int tid = threadIdx.x;

    __shared__ float hin[256];
    __shared__ float z1[128];
    __shared__ float z2[64];
    __shared__ float z3[32];

    hin[tid]       = h2[b * 256 + tid];
    hin[tid + 128] = h2[b * 256 + tid + 128];
    __syncthreads();

    {
        float a = bd1[tid];
#pragma unroll 8
        for (int i = 0; i < 256; ++i) a += hin[i] * Wd1[i * 128 + tid];
        z1[tid] = fmaxf(a, 0.0f);
    }
    __syncthreads();
    if (tid < 64) {
        float a = bd2[tid];
#pragma unroll 8
        for (int i = 0; i < 128; ++i) a += z1[i] * Wd2[i * 64 + tid];
        z2[tid] = fmaxf(a, 0.0f);
    }
    __syncthreads();
    if (tid < 32) {
        float a = bd3[tid];
#pragma unroll 8
        for (int i = 0; i < 64; ++i) a += z2[i] * Wd3[i * 32 + tid];
        z3[tid] = fmaxf(a, 0.0f);
    }
    __syncthreads();
    if (tid < NCLS) {
        float a = bd4[tid];
#pragma unroll
        for (int i = 0; i < 32; ++i) a += z3[i] * Wd4[i * NCLS + tid];
        out[b * NCLS + tid] = a;
    }
}

extern "C" void kernel_launch(void* const* d_in, const int* in_sizes, int n_in,
                              void* d_out, int out_size, void* d_ws, size_t ws_size,
                              hipStream_t stream) {
    const float* x   = (const float*)d_in[0];
    const float* W1  = (const float*)d_in[1];
    const float* U1  = (const float*)d_in[2];
    const float* b1  = (const float*)d_in[3];
    const float* W2  = (const float*)d_in[4];
    const float* U2  = (const float*)d_in[5];
    const float* b2  = (const float*)d_in[6];
    const float* Wd1 = (const float*)d_in[7];
    const float* bd1 = (const float*)d_in[8];
    const float* Wd2 = (const float*)d_in[9];
    const float* bd2 = (const float*)d_in[10];
    const float* Wd3 = (const float*)d_in[11];
    const float* bd3 = (const float*)d_in[12];
    const float* Wd4 = (const float*)d_in[13];
    const float* bd4 = (const float*)d_in[14];

    float* out = (float*)d_out;
    float* h2  = (float*)d_ws;        // 512*256 fp32

    rnn_fused_kernel<<<32, 512, 0, stream>>>(x, W1, U1, b1, W2, U2, b2, h2);
    mlp_kernel<<<512, 128, 0, stream>>>(h2, Wd1, bd1, Wd2, bd2, Wd3, bd3, Wd4, bd4, out);
}